// Round 9
// baseline (746.685 us; speedup 1.0000x reference)
//
#include <hip/hip_runtime.h>

#define N_NODES 100000
#define N_EDGES 1600000
#define D 128
#define NBUCK 98          // ceil(N_NODES / 1024), bucket = dst >> 10
#define CAP 20480         // ebuf slab capacity per bucket (raw edges); mean 16384, sigma~127
#define PCAP 28672        // csr slab capacity per bucket (%8-padded); max = CAP + 7*1024 = 27648
#define RSTRIDE_U32 800008   // (N_NODES+1) rows * 8 dwords per cg region
#define RSTRIDE_S 1600016    // same in shorts

typedef __attribute__((ext_vector_type(8))) short bf16x8;
typedef __attribute__((ext_vector_type(4))) float f32x4;
typedef unsigned long long u64;

__device__ __forceinline__ float b2f_lo(unsigned int u) {
    return __builtin_bit_cast(float, u << 16);
}
__device__ __forceinline__ float b2f_hi(unsigned int u) {
    return __builtin_bit_cast(float, u & 0xFFFF0000u);
}
__device__ __forceinline__ unsigned short f2b(float f) {
    unsigned int u = __builtin_bit_cast(unsigned int, f);
    u += 0x7FFFu + ((u >> 16) & 1u);
    return (unsigned short)(u >> 16);
}

// ---------------- prep: zero scratch + weights -> MFMA-fragment order + x -> cg layout ----------------
// xbT: 8 regions (cg = col/16), region cg = [node][16 cols] bf16 = 32B/row. With
// cg = blockIdx&7 pinned round-robin to XCDs, each XCD's gather working set is
// 3.2MB < 4MB L2 (R5: FETCH 188->55MB, verified). Wf: fragment order so each mlp
// b-load is one contiguous 1KB wave-read (R8: -74us, verified).

__global__ __launch_bounds__(256) void prep_kernel(
    const float* __restrict__ x, unsigned int* __restrict__ xbT,
    const float* __restrict__ W0, const float* __restrict__ W1_, const float* __restrict__ W2_,
    const float* __restrict__ W3, const float* __restrict__ W4, const float* __restrict__ W5,
    unsigned short* __restrict__ T0, unsigned short* __restrict__ T1_,
    unsigned short* __restrict__ T2_, unsigned short* __restrict__ T3,
    unsigned short* __restrict__ T4, unsigned short* __restrict__ T5,
    uint4* __restrict__ dob4) {
    int blk = blockIdx.x;
    if (blk < 384) {
        const float* W;
        unsigned short* T;
        switch (blk >> 6) {
            case 0: W = W0; T = T0; break;
            case 1: W = W1_; T = T1_; break;
            case 2: W = W2_; T = T2_; break;
            case 3: W = W3; T = T3; break;
            case 4: W = W4; T = T4; break;
            default: W = W5; T = T5; break;
        }
        int i = (blk & 63) * 256 + threadIdx.x;   // 0..16383, i = k*128 + n
        int k = i >> 7, n = i & 127;
        int nt = n >> 4, mr = n & 15;
        int kc = k >> 5, rem = k & 31, quad = rem >> 3, j = rem & 7;
        T[(nt * 4 + kc) * 512 + quad * 128 + mr * 8 + j] = f2b(W[i]);
    } else if (blk < 12884) {
        int i = (blk - 384) * 256 + threadIdx.x;  // float4 chunk id, 3,200,000 total
        if (i < 3200000) {
            float4 v = ((const float4*)x)[i];
            int r = i >> 5;          // node row
            int q = i & 31;          // float4 within row -> bf16 dwords 2q, 2q+1
            int dw = q * 2;
            int cg = dw >> 3;
            int cj = dw & 7;
            uint2 o;
            o.x = (unsigned int)f2b(v.x) | ((unsigned int)f2b(v.y) << 16);
            o.y = (unsigned int)f2b(v.z) | ((unsigned int)f2b(v.w) << 16);
            *(uint2*)(xbT + (size_t)cg * RSTRIDE_U32 + (size_t)r * 8 + cj) = o;
        }
    } else {
        int i = (blk - 12884) * 256 + threadIdx.x;
        uint4 z = {0u, 0u, 0u, 0u};
        if (i < 256) dob4[i] = z;     // zero d_out scratch head (bcur)
        if (i < 64) {                 // zero sentinel row N_NODES in each cg region
            int cg = i >> 3, c = i & 7;
            xbT[(size_t)cg * RSTRIDE_U32 + (size_t)N_NODES * 8 + c] = 0u;
        }
    }
}

// ---------------- CSR build (bucket-local, LDS atomics only, degrees padded to %8) ----------------

__global__ __launch_bounds__(256) void bin_kernel(const int* __restrict__ src,
                                                  const int* __restrict__ dst,
                                                  int* __restrict__ bcur,
                                                  u64* __restrict__ ebuf) {
    __shared__ int h[NBUCK];
    __shared__ int base[NBUCK];
    int tid = threadIdx.x;
    if (tid < NBUCK) h[tid] = 0;
    __syncthreads();
    int e0 = blockIdx.x * 2048;
    int myd[8], mys[8];
#pragma unroll
    for (int i = 0; i < 8; i++) {
        int e = e0 + tid + i * 256;
        int dv = (e < N_EDGES) ? dst[e] : -1;
        myd[i] = dv;
        mys[i] = (e < N_EDGES) ? src[e] : 0;
        if (dv >= 0) atomicAdd(&h[dv >> 10], 1);
    }
    __syncthreads();
    if (tid < NBUCK) {
        int c = h[tid];
        base[tid] = (c > 0) ? (tid * CAP + atomicAdd(&bcur[tid], c)) : 0;
        h[tid] = 0;
    }
    __syncthreads();
#pragma unroll
    for (int i = 0; i < 8; i++) {
        int dv = myd[i];
        if (dv >= 0) {
            int b = dv >> 10;
            int p = base[b] + atomicAdd(&h[b], 1);
            if (p < (b + 1) * CAP)
                ebuf[p] = ((u64)(unsigned int)dv << 32) | (unsigned int)mys[i];
        }
    }
}

// One kernel per bucket: LDS hist -> %8-padded LDS scan -> off/offe -> LDS-atomic
// scatter into the bucket's fixed-stride csr slab -> sentinel pads.
__global__ __launch_bounds__(1024) void bucket_all_kernel(const u64* __restrict__ ebuf,
                                                          const int* __restrict__ bcur,
                                                          int* __restrict__ off,
                                                          int* __restrict__ offe,
                                                          int* __restrict__ csr) {
    __shared__ int hist[1024];
    __shared__ int sc[1024];
    __shared__ int cnt[1024];
    int b = blockIdx.x, tid = threadIdx.x;
    int nE = bcur[b]; if (nE > CAP) nE = CAP;
    int base = b * PCAP;
    const u64* slab = ebuf + (size_t)b * CAP;
    hist[tid] = 0;
    cnt[tid] = 0;
    __syncthreads();
    for (int i = tid; i < nE; i += 1024)
        atomicAdd(&hist[(int)(slab[i] >> 32) & 1023], 1);
    __syncthreads();
    int node = b * 1024 + tid;
    int d = hist[tid];
    int dp = (node < N_NODES) ? ((d + 7) & ~7) : 0;
    sc[tid] = dp;
    __syncthreads();
#pragma unroll
    for (int s = 1; s < 1024; s <<= 1) {
        int t = (tid >= s) ? sc[tid - s] : 0;
        __syncthreads();
        sc[tid] += t;
        __syncthreads();
    }
    int excl = sc[tid] - dp;
    sc[tid] = excl;
    if (node < N_NODES) {
        off[node] = base + excl;
        offe[node] = base + excl + dp;
    }
    __syncthreads();
    for (int i = tid; i < nE; i += 1024) {
        u64 e = slab[i];
        int dd = (int)(e >> 32) & 1023;
        int pos = sc[dd] + atomicAdd(&cnt[dd], 1);
        csr[base + pos] = (int)(e & 0xFFFFFFFFu);
    }
    for (int j = d; j < dp; j++) csr[base + excl + j] = N_NODES;  // <=7 pads/node
}

// ---------------- aggregation over cg-sliced features ----------------
// cg = blockIdx&7 (XCD round-robin, R5-verified locality); ONE NODE PER WAVE:
// lane = (edge-slot e8 = lane>>3, col c = lane&7). Fixes R5's two stalls:
// (1) k-loop bounds wave-uniform -> no divergent per-group loops (R5 waves ran
// to max deg of 8 different nodes); (2) indices via one coalesced 64B csr read
// csr[k+e8] -> no ds_bpermute in the inner loop. 16 edges (2x 256B gathers) in
// flight. %8-padded CSR, sentinel row zero.

__global__ __launch_bounds__(256) void agg_cg(const unsigned int* __restrict__ xbT,
                                              const int* __restrict__ off,
                                              const int* __restrict__ offe,
                                              const int* __restrict__ csr,
                                              unsigned int* __restrict__ tT) {
    int cg = blockIdx.x & 7;
    int nb = blockIdx.x >> 3;                     // 0..24999
    int wave = threadIdx.x >> 6;                  // 4 waves -> 4 nodes/block
    int lane = threadIdx.x & 63;
    int e8 = lane >> 3, c = lane & 7;
    int node = nb * 4 + wave;                     // covers exactly 100000 nodes
    const unsigned int* xr = xbT + (size_t)cg * RSTRIDE_U32;
    unsigned int* tr = tT + (size_t)cg * RSTRIDE_U32;
    int k = off[node], e = offe[node];
    unsigned int me = xr[(size_t)node * 8 + c];
    float alo = (e8 == 0) ? b2f_lo(me) : 0.0f;
    float ahi = (e8 == 0) ? b2f_hi(me) : 0.0f;
    for (; k + 16 <= e; k += 16) {
        int i0 = csr[k + e8];
        int i1 = csr[k + 8 + e8];
        unsigned int v0 = xr[(size_t)i0 * 8 + c];
        unsigned int v1 = xr[(size_t)i1 * 8 + c];
        alo += b2f_lo(v0) + b2f_lo(v1);
        ahi += b2f_hi(v0) + b2f_hi(v1);
    }
    if (k < e) {   // %8 padding: remainder is exactly one 8-round
        int i0 = csr[k + e8];
        unsigned int v0 = xr[(size_t)i0 * 8 + c];
        alo += b2f_lo(v0);
        ahi += b2f_hi(v0);
    }
    // reduce the 8 edge-slot groups (lanes differing in bits 3..5)
    alo += __shfl_xor(alo, 8);  ahi += __shfl_xor(ahi, 8);
    alo += __shfl_xor(alo, 16); ahi += __shfl_xor(ahi, 16);
    alo += __shfl_xor(alo, 32); ahi += __shfl_xor(ahi, 32);
    if (e8 == 0)
        tr[(size_t)node * 8 + c] = (unsigned int)f2b(alo) | ((unsigned int)f2b(ahi) << 16);
}

// ---------------- fused MLP: y = relu(relu(t @ W1 + b1) @ W2 + b2) ----------------
// A from cg layout (R5-verified addressing); W in fragment order (R8-verified);
// 128-thr blocks (64 rows, grid 1563). bf16 output written back in cg layout.

template <bool OUT_F32>
__global__ __launch_bounds__(128) void mlp_mfma(const unsigned short* __restrict__ A,
                                                const unsigned short* __restrict__ W1f,
                                                const float* __restrict__ bias1,
                                                const unsigned short* __restrict__ W2f,
                                                const float* __restrict__ bias2,
                                                void* __restrict__ out) {
    __shared__ char smem[2 * 8704];
    int tid = threadIdx.x;
    int wave = tid >> 6, lane = tid & 63;
    int quad = lane >> 4, mr = lane & 15;
    int m_base = blockIdx.x * 64 + wave * 32;
    int m0 = m_base + mr;       if (m0 >= N_NODES) m0 = N_NODES - 1;
    int m1 = m_base + 16 + mr;  if (m1 >= N_NODES) m1 = N_NODES - 1;

    unsigned short* ust = (unsigned short*)(smem + wave * 8704);  // strip0 @0, strip1 @2176 shorts

    // ---- GEMM1: u = relu(t @ W1 + b1), both strips ----
    // cols [kc*32 + quad*8 .. +7] live in cg = 2*kc + (quad>>1), short offset (quad&1)*8
    bf16x8 a0[4], a1[4];
#pragma unroll
    for (int kc = 0; kc < 4; kc++) {
        size_t rb = (size_t)(2 * kc + (quad >> 1)) * RSTRIDE_S + (size_t)((quad & 1) * 8);
        a0[kc] = *(const bf16x8*)(A + rb + (size_t)m0 * 16);
        a1[kc] = *(const bf16x8*)(A + rb + (size_t)m1 * 16);
    }

    f32x4 acc0[8], acc1[8];
#pragma unroll
    for (int nt = 0; nt < 8; nt++) { acc0[nt] = (f32x4)0.0f; acc1[nt] = (f32x4)0.0f; }
#pragma unroll
    for (int nt = 0; nt < 8; nt++) {
#pragma unroll
        for (int kc = 0; kc < 4; kc++) {
            bf16x8 b = *(const bf16x8*)(W1f + (nt * 4 + kc) * 512 + lane * 8);
            acc0[nt] = __builtin_amdgcn_mfma_f32_16x16x32_bf16(a0[kc], b, acc0[nt], 0, 0, 0);
            acc1[nt] = __builtin_amdgcn_mfma_f32_16x16x32_bf16(a1[kc], b, acc1[nt], 0, 0, 0);
        }
    }
    // C layout: col(n) = mr, row(m in strip) = quad*4 + r
#pragma unroll
    for (int nt = 0; nt < 8; nt++) {
        float bv = bias1[nt * 16 + mr];
#pragma unroll
        for (int r = 0; r < 4; r++) {
            ust[(quad * 4 + r) * 136 + nt * 16 + mr] = f2b(fmaxf(acc0[nt][r] + bv, 0.0f));
            ust[2176 + (quad * 4 + r) * 136 + nt * 16 + mr] = f2b(fmaxf(acc1[nt][r] + bv, 0.0f));
        }
    }

    // ---- GEMM2: y = relu(u @ W2 + b2), both strips ----
#pragma unroll
    for (int kc = 0; kc < 4; kc++) {
        a0[kc] = *(const bf16x8*)&ust[mr * 136 + kc * 32 + quad * 8];
        a1[kc] = *(const bf16x8*)&ust[2176 + mr * 136 + kc * 32 + quad * 8];
    }
#pragma unroll
    for (int nt = 0; nt < 8; nt++) { acc0[nt] = (f32x4)0.0f; acc1[nt] = (f32x4)0.0f; }
#pragma unroll
    for (int nt = 0; nt < 8; nt++) {
#pragma unroll
        for (int kc = 0; kc < 4; kc++) {
            bf16x8 b = *(const bf16x8*)(W2f + (nt * 4 + kc) * 512 + lane * 8);
            acc0[nt] = __builtin_amdgcn_mfma_f32_16x16x32_bf16(a0[kc], b, acc0[nt], 0, 0, 0);
            acc1[nt] = __builtin_amdgcn_mfma_f32_16x16x32_bf16(a1[kc], b, acc1[nt], 0, 0, 0);
        }
    }

    // ---- epilogue ----
    if (OUT_F32) {
        float* st = (float*)ust;   // 16 x 132 f32 = 8448 B <= 8704 B
        const int S = 132;
        float* op = (float*)out;
#pragma unroll
        for (int s = 0; s < 2; s++) {
#pragma unroll
            for (int nt = 0; nt < 8; nt++) {
                float bv = bias2[nt * 16 + mr];
#pragma unroll
                for (int r = 0; r < 4; r++) {
                    float v = s ? acc1[nt][r] : acc0[nt][r];
                    st[(quad * 4 + r) * S + nt * 16 + mr] = fmaxf(v + bv, 0.0f);
                }
            }
#pragma unroll
            for (int it = 0; it < 8; it++) {
                int linear = lane + it * 64;
                int row = linear >> 5, col = (linear & 31) << 2;
                int gm = m_base + s * 16 + row;
                if (gm < N_NODES) {
                    float4 val = *(float4*)&st[row * S + col];
                    *(float4*)(op + (size_t)gm * D + col) = val;
                }
            }
        }
    } else {
        const int S = 136;
        unsigned short* op = (unsigned short*)out;   // xbT base (cg layout)
#pragma unroll
        for (int s = 0; s < 2; s++) {
            unsigned short* st = ust + s * 2176;
#pragma unroll
            for (int nt = 0; nt < 8; nt++) {
                float bv = bias2[nt * 16 + mr];
#pragma unroll
                for (int r = 0; r < 4; r++) {
                    float v = s ? acc1[nt][r] : acc0[nt][r];
                    st[(quad * 4 + r) * S + nt * 16 + mr] = f2b(fmaxf(v + bv, 0.0f));
                }
            }
#pragma unroll
            for (int it = 0; it < 4; it++) {
                int linear = lane + it * 64;
                int row = linear >> 4, colst = (linear & 15) << 3;  // colst in {0,8,...,120}
                int gm = m_base + s * 16 + row;
                if (gm < N_NODES) {
                    uint4 val = *(uint4*)&st[row * S + colst];
                    unsigned short* dp = op + (size_t)(colst >> 4) * RSTRIDE_S
                                       + (size_t)gm * 16 + (colst & 15);
                    *(uint4*)dp = val;
                }
            }
        }
    }
}

// ---------------- launch ----------------

extern "C" void kernel_launch(void* const* d_in, const int* in_sizes, int n_in,
                              void* d_out, int out_size, void* d_ws, size_t ws_size,
                              hipStream_t stream) {
    const float* x = (const float*)d_in[0];
    const int* ei = (const int*)d_in[1];
    const int* srcv = ei;
    const int* dstv = ei + N_EDGES;
    const float* W1[3] = {(const float*)d_in[2], (const float*)d_in[6], (const float*)d_in[10]};
    const float* b1[3] = {(const float*)d_in[3], (const float*)d_in[7], (const float*)d_in[11]};
    const float* W2[3] = {(const float*)d_in[4], (const float*)d_in[8], (const float*)d_in[12]};
    const float* b2[3] = {(const float*)d_in[5], (const float*)d_in[9], (const float*)d_in[13]};

    // ws layout (high-water 52,249,088):
    char* ws = (char*)d_ws;
    int* off  = (int*)ws;                                    // N ints @ 0
    int* offe = (int*)(ws + 400000);                         // N ints
    unsigned short* Wt[6];                                   // 6 x 32KB @ 800,000 (fragment order)
    for (int i = 0; i < 6; i++) Wt[i] = (unsigned short*)(ws + 800000 + i * 32768);
    unsigned short* xbT = (unsigned short*)(ws + 1048576);   // 8 cg regions, 25,600,256 B
    unsigned short* PT  = (unsigned short*)(ws + 26648832);  // same, ends 52,249,088

    // d_out scratch (all dead before the final mlp writes d_out):
    char* dob = (char*)d_out;
    int* bcur = (int*)(dob);                // NBUCK ints (zeroed by prep)
    u64* ebuf = (u64*)(dob + 1048576);      // NBUCK*CAP u64 = 16.06MB, ends 17,104,896
    int* csr  = (int*)(dob + 17104896);     // NBUCK*PCAP ints = 11.24MB, ends 28,344,320

    // --- prep: zero bcur + sentinel rows + weights->fragment order + x->cg layout ---
    prep_kernel<<<12885, 256, 0, stream>>>(
        x, (unsigned int*)xbT,
        W1[0], W2[0], W1[1], W2[1], W1[2], W2[2],
        Wt[0], Wt[1], Wt[2], Wt[3], Wt[4], Wt[5],
        (uint4*)dob);

    // --- CSR build: 2 kernels (bin -> fused hist/scan/scatter per bucket, %8 pad) ---
    bin_kernel<<<782, 256, 0, stream>>>(srcv, dstv, bcur, ebuf);
    bucket_all_kernel<<<NBUCK, 1024, 0, stream>>>(ebuf, bcur, off, offe, csr);

    const int agg_grid = 200000;                       // 8 cg x 25000; 4 nodes/block, 1 node/wave
    const int mlp_grid = 1563;                         // 64 rows/block, 2 waves

    // layer 0: agg xbT->PT, mlp PT->xbT
    agg_cg<<<agg_grid, 256, 0, stream>>>((const unsigned int*)xbT, off, offe, csr, (unsigned int*)PT);
    mlp_mfma<false><<<mlp_grid, 128, 0, stream>>>(PT, Wt[0], b1[0], Wt[1], b2[0], xbT);
    // layer 1
    agg_cg<<<agg_grid, 256, 0, stream>>>((const unsigned int*)xbT, off, offe, csr, (unsigned int*)PT);
    mlp_mfma<false><<<mlp_grid, 128, 0, stream>>>(PT, Wt[2], b1[1], Wt[3], b2[1], xbT);
    // layer 2
    agg_cg<<<agg_grid, 256, 0, stream>>>((const unsigned int*)xbT, off, offe, csr, (unsigned int*)PT);
    mlp_mfma<true><<<mlp_grid, 128, 0, stream>>>(PT, Wt[4], b1[2], Wt[5], b2[2], d_out);
}

// Round 10
// 526.724 us; speedup vs baseline: 1.4176x; 1.4176x over previous
//
#include <hip/hip_runtime.h>

#define N_NODES 100000
#define N_EDGES 1600000
#define D 128
#define NBUCK 98          // ceil(N_NODES / 1024), bucket = dst >> 10
#define CAP 20480         // ebuf slab capacity per bucket (raw edges); mean 16384, sigma~127
#define PCAP 24576        // csr slab capacity per bucket (%4-padded); max = CAP + 3*1024 = 23552

typedef __attribute__((ext_vector_type(8))) short bf16x8;
typedef __attribute__((ext_vector_type(4))) float f32x4;
typedef unsigned long long u64;

__device__ __forceinline__ float b2f_lo(unsigned int u) {
    return __builtin_bit_cast(float, u << 16);
}
__device__ __forceinline__ float b2f_hi(unsigned int u) {
    return __builtin_bit_cast(float, u & 0xFFFF0000u);
}
__device__ __forceinline__ unsigned short f2b(float f) {
    unsigned int u = __builtin_bit_cast(unsigned int, f);
    u += 0x7FFFu + ((u >> 16) & 1u);
    return (unsigned short)(u >> 16);
}

// ---------------- prep: zero scratch + weights -> MFMA-fragment order + convert x ----------------

__global__ __launch_bounds__(256) void prep_kernel(
    const float* __restrict__ x, unsigned short* __restrict__ xb,
    const float* __restrict__ W0, const float* __restrict__ W1_, const float* __restrict__ W2_,
    const float* __restrict__ W3, const float* __restrict__ W4, const float* __restrict__ W5,
    unsigned short* __restrict__ T0, unsigned short* __restrict__ T1_,
    unsigned short* __restrict__ T2_, unsigned short* __restrict__ T3,
    unsigned short* __restrict__ T4, unsigned short* __restrict__ T5,
    uint4* __restrict__ dob4, uint4* __restrict__ xs0, uint4* __restrict__ xs1) {
    int blk = blockIdx.x;
    if (blk < 384) {
        const float* W;
        unsigned short* T;
        switch (blk >> 6) {
            case 0: W = W0; T = T0; break;
            case 1: W = W1_; T = T1_; break;
            case 2: W = W2_; T = T2_; break;
            case 3: W = W3; T = T3; break;
            case 4: W = W4; T = T4; break;
            default: W = W5; T = T5; break;
        }
        int i = (blk & 63) * 256 + threadIdx.x;   // 0..16383, i = k*128 + n
        int k = i >> 7, n = i & 127;
        int nt = n >> 4, mr = n & 15;
        int kc = k >> 5, rem = k & 31, quad = rem >> 3, j = rem & 7;
        T[(nt * 4 + kc) * 512 + quad * 128 + mr * 8 + j] = f2b(W[i]);
    } else if (blk < 12884) {
        int i = (blk - 384) * 256 + threadIdx.x;  // float4 chunks, 3,200,000 total
        if (i < 3200000) {
            float4 v = ((const float4*)x)[i];
            ushort4 o;
            o.x = f2b(v.x); o.y = f2b(v.y); o.z = f2b(v.z); o.w = f2b(v.w);
            ((ushort4*)xb)[i] = o;
        }
    } else {
        int i = (blk - 12884) * 256 + threadIdx.x;
        uint4 z = {0u, 0u, 0u, 0u};
        if (i < 256) dob4[i] = z;                 // zero d_out scratch head (bcur)
        if (i < 16) { xs0[i] = z; xs1[i] = z; }   // zero sentinel rows of both buffers
    }
}

// ---------------- CSR build (bucket-local, LDS atomics only, degrees padded to %4) ----------------

__global__ __launch_bounds__(256) void bin_kernel(const int* __restrict__ src,
                                                  const int* __restrict__ dst,
                                                  int* __restrict__ bcur,
                                                  u64* __restrict__ ebuf) {
    __shared__ int h[NBUCK];
    __shared__ int base[NBUCK];
    int tid = threadIdx.x;
    if (tid < NBUCK) h[tid] = 0;
    __syncthreads();
    int e0 = blockIdx.x * 2048;
    int myd[8], mys[8];
#pragma unroll
    for (int i = 0; i < 8; i++) {
        int e = e0 + tid + i * 256;
        int dv = (e < N_EDGES) ? dst[e] : -1;
        myd[i] = dv;
        mys[i] = (e < N_EDGES) ? src[e] : 0;
        if (dv >= 0) atomicAdd(&h[dv >> 10], 1);
    }
    __syncthreads();
    if (tid < NBUCK) {
        int c = h[tid];
        base[tid] = (c > 0) ? (tid * CAP + atomicAdd(&bcur[tid], c)) : 0;
        h[tid] = 0;
    }
    __syncthreads();
#pragma unroll
    for (int i = 0; i < 8; i++) {
        int dv = myd[i];
        if (dv >= 0) {
            int b = dv >> 10;
            int p = base[b] + atomicAdd(&h[b], 1);
            if (p < (b + 1) * CAP)
                ebuf[p] = ((u64)(unsigned int)dv << 32) | (unsigned int)mys[i];
        }
    }
}

// One kernel per bucket: LDS hist -> %4-padded LDS scan -> off/offe -> LDS-atomic
// scatter into the bucket's fixed-stride csr slab -> sentinel pads.
__global__ __launch_bounds__(1024) void bucket_all_kernel(const u64* __restrict__ ebuf,
                                                          const int* __restrict__ bcur,
                                                          int* __restrict__ off,
                                                          int* __restrict__ offe,
                                                          int* __restrict__ csr) {
    __shared__ int hist[1024];
    __shared__ int sc[1024];
    __shared__ int cnt[1024];
    int b = blockIdx.x, tid = threadIdx.x;
    int nE = bcur[b]; if (nE > CAP) nE = CAP;
    int base = b * PCAP;
    const u64* slab = ebuf + (size_t)b * CAP;
    hist[tid] = 0;
    cnt[tid] = 0;
    __syncthreads();
    for (int i = tid; i < nE; i += 1024)
        atomicAdd(&hist[(int)(slab[i] >> 32) & 1023], 1);
    __syncthreads();
    int node = b * 1024 + tid;
    int d = hist[tid];
    int dp = (node < N_NODES) ? ((d + 3) & ~3) : 0;
    sc[tid] = dp;
    __syncthreads();
#pragma unroll
    for (int s = 1; s < 1024; s <<= 1) {
        int t = (tid >= s) ? sc[tid - s] : 0;
        __syncthreads();
        sc[tid] += t;
        __syncthreads();
    }
    int excl = sc[tid] - dp;
    sc[tid] = excl;
    if (node < N_NODES) {
        off[node] = base + excl;
        offe[node] = base + excl + dp;
    }
    __syncthreads();
    for (int i = tid; i < nE; i += 1024) {
        u64 e = slab[i];
        int dd = (int)(e >> 32) & 1023;
        int pos = sc[dd] + atomicAdd(&cnt[dd], 1);
        csr[base + pos] = (int)(e & 0xFFFFFFFFu);
    }
    for (int j = d; j < dp; j++) csr[base + excl + j] = N_NODES;  // <=3 pads/node
}

// ---------------- standalone aggregation (layer 2): R8-verified, 58.4us ----------------

__global__ __launch_bounds__(256) void agg_bf16(const unsigned int* __restrict__ xb,
                                                const int* __restrict__ off,
                                                const int* __restrict__ offe,
                                                const int* __restrict__ csr,
                                                unsigned int* __restrict__ t) {
    int node = blockIdx.x * 4 + (threadIdx.x >> 6);
    int lane = threadIdx.x & 63;
    unsigned int v = xb[(size_t)node * 64 + lane];
    float ax = b2f_lo(v), ay = b2f_hi(v);
    int k = off[node], e = offe[node];
    for (; k + 16 <= e; k += 16) {
        int idx[16];
        unsigned int g[16];
#pragma unroll
        for (int i = 0; i < 16; i++) idx[i] = csr[k + i];
#pragma unroll
        for (int i = 0; i < 16; i++) g[i] = xb[(size_t)idx[i] * 64 + lane];
#pragma unroll
        for (int i = 0; i < 16; i++) { ax += b2f_lo(g[i]); ay += b2f_hi(g[i]); }
    }
    if (k + 8 <= e) {
        int idx[8];
        unsigned int g[8];
#pragma unroll
        for (int i = 0; i < 8; i++) idx[i] = csr[k + i];
#pragma unroll
        for (int i = 0; i < 8; i++) g[i] = xb[(size_t)idx[i] * 64 + lane];
#pragma unroll
        for (int i = 0; i < 8; i++) { ax += b2f_lo(g[i]); ay += b2f_hi(g[i]); }
        k += 8;
    }
    if (k < e) {
        int idx[4];
        unsigned int g[4];
#pragma unroll
        for (int i = 0; i < 4; i++) idx[i] = csr[k + i];
#pragma unroll
        for (int i = 0; i < 4; i++) g[i] = xb[(size_t)idx[i] * 64 + lane];
#pragma unroll
        for (int i = 0; i < 4; i++) { ax += b2f_lo(g[i]); ay += b2f_hi(g[i]); }
    }
    t[(size_t)node * 64 + lane] = (unsigned int)f2b(ax) | ((unsigned int)f2b(ay) << 16);
}

// ---------------- fused GIN layer (layers 0,1): agg -> GEMM1 -> relu -> GEMM2 -> relu ----------------
// R6 retry with the occupancy failure fixed: 256-thread / 4-wave blocks (R6's
// 64-thread blocks hit the per-CU workgroup cap -> 21% occupancy). 128 rows per
// block; each wave aggregates its 32 rows (R8 gather structure, 16 in flight)
// into its wave-private 8704B LDS tile at stride 136 shorts (= GEMM1's A layout),
// then runs R8's verified 2-strip MFMA pipeline with fragment-order W. No
// __syncthreads (all LDS wave-private). Kills P round-trip (~51MB/layer) + 1 gap.

template <bool OUT_F32>
__global__ __launch_bounds__(256) void gin_fused(const unsigned int* __restrict__ xbu,
                                                 const int* __restrict__ off,
                                                 const int* __restrict__ offe,
                                                 const int* __restrict__ csr,
                                                 const unsigned short* __restrict__ W1f,
                                                 const float* __restrict__ bias1,
                                                 const unsigned short* __restrict__ W2f,
                                                 const float* __restrict__ bias2,
                                                 void* __restrict__ out) {
    __shared__ unsigned int smem[4 * 2176];       // 4 waves x 8704 B
    int tid = threadIdx.x;
    int wave = tid >> 6, lane = tid & 63;
    int quad = lane >> 4, mr = lane & 15;
    int m_base = blockIdx.x * 128 + wave * 32;
    unsigned int* wreg = smem + wave * 2176;
    unsigned short* ust = (unsigned short*)wreg;

    // ---- phase 1: aggregate 32 rows into the wave tile ----
    for (int s = 0; s < 32; s++) {
        int node = m_base + s;
        if (node >= N_NODES) node = N_NODES - 1;   // last block only; stores masked later
        unsigned int me = xbu[(size_t)node * 64 + lane];
        float ax = b2f_lo(me), ay = b2f_hi(me);
        int k = off[node], e = offe[node];
        for (; k + 16 <= e; k += 16) {
            int idx[16];
            unsigned int g[16];
#pragma unroll
            for (int i = 0; i < 16; i++) idx[i] = csr[k + i];
#pragma unroll
            for (int i = 0; i < 16; i++) g[i] = xbu[(size_t)idx[i] * 64 + lane];
#pragma unroll
            for (int i = 0; i < 16; i++) { ax += b2f_lo(g[i]); ay += b2f_hi(g[i]); }
        }
        if (k + 8 <= e) {
            int idx[8];
            unsigned int g[8];
#pragma unroll
            for (int i = 0; i < 8; i++) idx[i] = csr[k + i];
#pragma unroll
            for (int i = 0; i < 8; i++) g[i] = xbu[(size_t)idx[i] * 64 + lane];
#pragma unroll
            for (int i = 0; i < 8; i++) { ax += b2f_lo(g[i]); ay += b2f_hi(g[i]); }
            k += 8;
        }
        if (k < e) {
            int idx[4];
            unsigned int g[4];
#pragma unroll
            for (int i = 0; i < 4; i++) idx[i] = csr[k + i];
#pragma unroll
            for (int i = 0; i < 4; i++) g[i] = xbu[(size_t)idx[i] * 64 + lane];
#pragma unroll
            for (int i = 0; i < 4; i++) { ax += b2f_lo(g[i]); ay += b2f_hi(g[i]); }
        }
        wreg[s * 68 + lane] = (unsigned int)f2b(ax) | ((unsigned int)f2b(ay) << 16);
    }

    // ---- GEMM1: u = relu(t @ W1 + b1), A-frags from the wave tile ----
    bf16x8 a0[4], a1[4];
#pragma unroll
    for (int kc = 0; kc < 4; kc++) {
        a0[kc] = *(const bf16x8*)&ust[mr * 136 + kc * 32 + quad * 8];
        a1[kc] = *(const bf16x8*)&ust[2176 + mr * 136 + kc * 32 + quad * 8];
    }

    f32x4 acc0[8], acc1[8];
#pragma unroll
    for (int nt = 0; nt < 8; nt++) { acc0[nt] = (f32x4)0.0f; acc1[nt] = (f32x4)0.0f; }
#pragma unroll
    for (int nt = 0; nt < 8; nt++) {
#pragma unroll
        for (int kc = 0; kc < 4; kc++) {
            bf16x8 b = *(const bf16x8*)(W1f + (nt * 4 + kc) * 512 + lane * 8);
            acc0[nt] = __builtin_amdgcn_mfma_f32_16x16x32_bf16(a0[kc], b, acc0[nt], 0, 0, 0);
            acc1[nt] = __builtin_amdgcn_mfma_f32_16x16x32_bf16(a1[kc], b, acc1[nt], 0, 0, 0);
        }
    }
    // C layout: col(n) = mr, row(m in strip) = quad*4 + r
#pragma unroll
    for (int nt = 0; nt < 8; nt++) {
        float bv = bias1[nt * 16 + mr];
#pragma unroll
        for (int r = 0; r < 4; r++) {
            ust[(quad * 4 + r) * 136 + nt * 16 + mr] = f2b(fmaxf(acc0[nt][r] + bv, 0.0f));
            ust[2176 + (quad * 4 + r) * 136 + nt * 16 + mr] = f2b(fmaxf(acc1[nt][r] + bv, 0.0f));
        }
    }

    // ---- GEMM2: y = relu(u @ W2 + b2) ----
#pragma unroll
    for (int kc = 0; kc < 4; kc++) {
        a0[kc] = *(const bf16x8*)&ust[mr * 136 + kc * 32 + quad * 8];
        a1[kc] = *(const bf16x8*)&ust[2176 + mr * 136 + kc * 32 + quad * 8];
    }
#pragma unroll
    for (int nt = 0; nt < 8; nt++) { acc0[nt] = (f32x4)0.0f; acc1[nt] = (f32x4)0.0f; }
#pragma unroll
    for (int nt = 0; nt < 8; nt++) {
#pragma unroll
        for (int kc = 0; kc < 4; kc++) {
            bf16x8 b = *(const bf16x8*)(W2f + (nt * 4 + kc) * 512 + lane * 8);
            acc0[nt] = __builtin_amdgcn_mfma_f32_16x16x32_bf16(a0[kc], b, acc0[nt], 0, 0, 0);
            acc1[nt] = __builtin_amdgcn_mfma_f32_16x16x32_bf16(a1[kc], b, acc1[nt], 0, 0, 0);
        }
    }

    // ---- epilogue: stage strips in the wave tile, coalesced store ----
    if (OUT_F32) {
        float* st = (float*)wreg;   // 16 x 132 f32 = 8448 B <= 8704 B
        const int S = 132;
        float* op = (float*)out;
#pragma unroll
        for (int s = 0; s < 2; s++) {
#pragma unroll
            for (int nt = 0; nt < 8; nt++) {
                float bv = bias2[nt * 16 + mr];
#pragma unroll
                for (int r = 0; r < 4; r++) {
                    float v = s ? acc1[nt][r] : acc0[nt][r];
                    st[(quad * 4 + r) * S + nt * 16 + mr] = fmaxf(v + bv, 0.0f);
                }
            }
#pragma unroll
            for (int it = 0; it < 8; it++) {
                int linear = lane + it * 64;
                int row = linear >> 5, col = (linear & 31) << 2;
                int gm = m_base + s * 16 + row;
                if (gm < N_NODES) {
                    float4 val = *(float4*)&st[row * S + col];
                    *(float4*)(op + (size_t)gm * D + col) = val;
                }
            }
        }
    } else {
        const int S = 136;
        unsigned short* op = (unsigned short*)out;
#pragma unroll
        for (int s = 0; s < 2; s++) {
            unsigned short* st = ust + s * 2176;
#pragma unroll
            for (int nt = 0; nt < 8; nt++) {
                float bv = bias2[nt * 16 + mr];
#pragma unroll
                for (int r = 0; r < 4; r++) {
                    float v = s ? acc1[nt][r] : acc0[nt][r];
                    st[(quad * 4 + r) * S + nt * 16 + mr] = f2b(fmaxf(v + bv, 0.0f));
                }
            }
#pragma unroll
            for (int it = 0; it < 4; it++) {
                int linear = lane + it * 64;
                int row = linear >> 4, col = (linear & 15) << 3;
                int gm = m_base + s * 16 + row;
                if (gm < N_NODES) {
                    uint4 val = *(uint4*)&st[row * S + col];
                    *(uint4*)(op + (size_t)gm * D + col) = val;
                }
            }
        }
    }
}

// ---------------- standalone MLP (layer 2): R8-verified ----------------

template <bool OUT_F32>
__global__ __launch_bounds__(128) void mlp_mfma(const unsigned short* __restrict__ A,
                                                const unsigned short* __restrict__ W1f,
                                                const float* __restrict__ bias1,
                                                const unsigned short* __restrict__ W2f,
                                                const float* __restrict__ bias2,
                                                void* __restrict__ out) {
    __shared__ char smem[2 * 8704];
    int tid = threadIdx.x;
    int wave = tid >> 6, lane = tid & 63;
    int quad = lane >> 4, mr = lane & 15;
    int m_base = blockIdx.x * 64 + wave * 32;
    int m0 = m_base + mr;       if (m0 >= N_NODES) m0 = N_NODES - 1;
    int m1 = m_base + 16 + mr;  if (m1 >= N_NODES) m1 = N_NODES - 1;

    unsigned short* ust = (unsigned short*)(smem + wave * 8704);

    bf16x8 a0[4], a1[4];
#pragma unroll
    for (int kc = 0; kc < 4; kc++) {
        a0[kc] = *(const bf16x8*)(A + (size_t)m0 * D + kc * 32 + quad * 8);
        a1[kc] = *(const bf16x8*)(A + (size_t)m1 * D + kc * 32 + quad * 8);
    }

    f32x4 acc0[8], acc1[8];
#pragma unroll
    for (int nt = 0; nt < 8; nt++) { acc0[nt] = (f32x4)0.0f; acc1[nt] = (f32x4)0.0f; }
#pragma unroll
    for (int nt = 0; nt < 8; nt++) {
#pragma unroll
        for (int kc = 0; kc < 4; kc++) {
            bf16x8 b = *(const bf16x8*)(W1f + (nt * 4 + kc) * 512 + lane * 8);
            acc0[nt] = __builtin_amdgcn_mfma_f32_16x16x32_bf16(a0[kc], b, acc0[nt], 0, 0, 0);
            acc1[nt] = __builtin_amdgcn_mfma_f32_16x16x32_bf16(a1[kc], b, acc1[nt], 0, 0, 0);
        }
    }
#pragma unroll
    for (int nt = 0; nt < 8; nt++) {
        float bv = bias1[nt * 16 + mr];
#pragma unroll
        for (int r = 0; r < 4; r++) {
            ust[(quad * 4 + r) * 136 + nt * 16 + mr] = f2b(fmaxf(acc0[nt][r] + bv, 0.0f));
            ust[2176 + (quad * 4 + r) * 136 + nt * 16 + mr] = f2b(fmaxf(acc1[nt][r] + bv, 0.0f));
        }
    }

#pragma unroll
    for (int kc = 0; kc < 4; kc++) {
        a0[kc] = *(const bf16x8*)&ust[mr * 136 + kc * 32 + quad * 8];
        a1[kc] = *(const bf16x8*)&ust[2176 + mr * 136 + kc * 32 + quad * 8];
    }
#pragma unroll
    for (int nt = 0; nt < 8; nt++) { acc0[nt] = (f32x4)0.0f; acc1[nt] = (f32x4)0.0f; }
#pragma unroll
    for (int nt = 0; nt < 8; nt++) {
#pragma unroll
        for (int kc = 0; kc < 4; kc++) {
            bf16x8 b = *(const bf16x8*)(W2f + (nt * 4 + kc) * 512 + lane * 8);
            acc0[nt] = __builtin_amdgcn_mfma_f32_16x16x32_bf16(a0[kc], b, acc0[nt], 0, 0, 0);
            acc1[nt] = __builtin_amdgcn_mfma_f32_16x16x32_bf16(a1[kc], b, acc1[nt], 0, 0, 0);
        }
    }

    if (OUT_F32) {
        float* st = (float*)ust;
        const int S = 132;
        float* op = (float*)out;
#pragma unroll
        for (int s = 0; s < 2; s++) {
#pragma unroll
            for (int nt = 0; nt < 8; nt++) {
                float bv = bias2[nt * 16 + mr];
#pragma unroll
                for (int r = 0; r < 4; r++) {
                    float v = s ? acc1[nt][r] : acc0[nt][r];
                    st[(quad * 4 + r) * S + nt * 16 + mr] = fmaxf(v + bv, 0.0f);
                }
            }
#pragma unroll
            for (int it = 0; it < 8; it++) {
                int linear = lane + it * 64;
                int row = linear >> 5, col = (linear & 31) << 2;
                int gm = m_base + s * 16 + row;
                if (gm < N_NODES) {
                    float4 val = *(float4*)&st[row * S + col];
                    *(float4*)(op + (size_t)gm * D + col) = val;
                }
            }
        }
    } else {
        const int S = 136;
        unsigned short* op = (unsigned short*)out;
#pragma unroll
        for (int s = 0; s < 2; s++) {
            unsigned short* st = ust + s * 2176;
#pragma unroll
            for (int nt = 0; nt < 8; nt++) {
                float bv = bias2[nt * 16 + mr];
#pragma unroll
                for (int r = 0; r < 4; r++) {
                    float v = s ? acc1[nt][r] : acc0[nt][r];
                    st[(quad * 4 + r) * S + nt * 16 + mr] = f2b(fmaxf(v + bv, 0.0f));
                }
            }
#pragma unroll
            for (int it = 0; it < 4; it++) {
                int linear = lane + it * 64;
                int row = linear >> 4, col = (linear & 15) << 3;
                int gm = m_base + s * 16 + row;
                if (gm < N_NODES) {
                    uint4 val = *(uint4*)&st[row * S + col];
                    *(uint4*)(op + (size_t)gm * D + col) = val;
                }
            }
        }
    }
}

// ---------------- launch ----------------

extern "C" void kernel_launch(void* const* d_in, const int* in_sizes, int n_in,
                              void* d_out, int out_size, void* d_ws, size_t ws_size,
                              hipStream_t stream) {
    const float* x = (const float*)d_in[0];
    const int* ei = (const int*)d_in[1];
    const int* srcv = ei;
    const int* dstv = ei + N_EDGES;
    const float* W1[3] = {(const float*)d_in[2], (const float*)d_in[6], (const float*)d_in[10]};
    const float* b1[3] = {(const float*)d_in[3], (const float*)d_in[7], (const float*)d_in[11]};
    const float* W2[3] = {(const float*)d_in[4], (const float*)d_in[8], (const float*)d_in[12]};
    const float* b2[3] = {(const float*)d_in[5], (const float*)d_in[9], (const float*)d_in[13]};

    // ws layout (high-water 52,249,088):
    char* ws = (char*)d_ws;
    int* off  = (int*)ws;                                    // N ints @ 0
    int* offe = (int*)(ws + 400000);                         // N ints
    unsigned short* Wt[6];                                   // 6 x 32KB @ 800,000 (fragment order)
    for (int i = 0; i < 6; i++) Wt[i] = (unsigned short*)(ws + 800000 + i * 32768);
    unsigned short* xb0 = (unsigned short*)(ws + 1048576);   // (N+1)*256 B, sentinel row N
    unsigned short* xb1 = (unsigned short*)(ws + 26648832);  // (N+1)*256 B, sentinel row N

    // d_out scratch (all reads complete before mlp<true> writes d_out: csr/off
    // last read by layer-2 agg, which precedes the final mlp):
    char* dob = (char*)d_out;
    int* bcur = (int*)(dob);                // NBUCK ints (zeroed by prep)
    u64* ebuf = (u64*)(dob + 1048576);      // NBUCK*CAP u64 = 16.06MB, ends 17,104,896
    int* csr  = (int*)(dob + 17104896);     // NBUCK*PCAP ints = 9.63MB, ends 26,738,688

    // --- prep: zero bcur + sentinel rows + weights->fragment order + convert x ---
    prep_kernel<<<12885, 256, 0, stream>>>(
        x, xb0,
        W1[0], W2[0], W1[1], W2[1], W1[2], W2[2],
        Wt[0], Wt[1], Wt[2], Wt[3], Wt[4], Wt[5],
        (uint4*)dob,
        (uint4*)(xb0 + (size_t)N_NODES * D),
        (uint4*)(xb1 + (size_t)N_NODES * D));

    // --- CSR build: 2 kernels ---
    bin_kernel<<<782, 256, 0, stream>>>(srcv, dstv, bcur, ebuf);
    bucket_all_kernel<<<NBUCK, 1024, 0, stream>>>(ebuf, bcur, off, offe, csr);

    // layers 0,1: fused (4-wave blocks, 128 rows each), ping-pong xb0/xb1
    gin_fused<false><<<782, 256, 0, stream>>>((const unsigned int*)xb0, off, offe, csr,
                                              Wt[0], b1[0], Wt[1], b2[0], xb1);
    gin_fused<false><<<782, 256, 0, stream>>>((const unsigned int*)xb1, off, offe, csr,
                                              Wt[2], b1[1], Wt[3], b2[1], xb0);
    // layer 2: split (csr lives in d_out scratch; all csr reads must precede
    // the d_out-writing MLP). P reuses xb1.
    agg_bf16<<<25000, 256, 0, stream>>>((const unsigned int*)xb0, off, offe, csr,
                                        (unsigned int*)xb1);
    mlp_mfma<true><<<1563, 128, 0, stream>>>(xb1, Wt[4], b1[2], Wt[5], b2[2], d_out);
}

// Round 11
// 413.427 us; speedup vs baseline: 1.8061x; 1.2740x over previous
//
#include <hip/hip_runtime.h>

#define N_NODES 100000
#define N_EDGES 1600000
#define D 128
#define NBUCK 98          // ceil(N_NODES / 1024), bucket = dst >> 10
#define CAP 20480         // ebuf slab capacity per bucket (raw edges); mean 16384, sigma~127
#define PCAP 24576        // csr slab capacity per bucket (%4-padded); max = CAP + 3*1024 = 23552
#define NBLK32 3125       // N_NODES / 32 row-blocks (exact)

typedef __attribute__((ext_vector_type(8))) short bf16x8;
typedef __attribute__((ext_vector_type(4))) float f32x4;
typedef unsigned long long u64;

__device__ __forceinline__ float b2f_lo(unsigned int u) {
    return __builtin_bit_cast(float, u << 16);
}
__device__ __forceinline__ float b2f_hi(unsigned int u) {
    return __builtin_bit_cast(float, u & 0xFFFF0000u);
}
__device__ __forceinline__ unsigned short f2b(float f) {
    unsigned int u = __builtin_bit_cast(unsigned int, f);
    u += 0x7FFFu + ((u >> 16) & 1u);
    return (unsigned short)(u >> 16);
}

// ---------------- prep: zero scratch + weights -> MFMA-fragment order + convert x ----------------

__global__ __launch_bounds__(256) void prep_kernel(
    const float* __restrict__ x, unsigned short* __restrict__ xb,
    const float* __restrict__ W0, const float* __restrict__ W1_, const float* __restrict__ W2_,
    const float* __restrict__ W3, const float* __restrict__ W4, const float* __restrict__ W5,
    unsigned short* __restrict__ T0, unsigned short* __restrict__ T1_,
    unsigned short* __restrict__ T2_, unsigned short* __restrict__ T3,
    unsigned short* __restrict__ T4, unsigned short* __restrict__ T5,
    uint4* __restrict__ dob4, uint4* __restrict__ xs0) {
    int blk = blockIdx.x;
    if (blk < 384) {
        const float* W;
        unsigned short* T;
        switch (blk >> 6) {
            case 0: W = W0; T = T0; break;
            case 1: W = W1_; T = T1_; break;
            case 2: W = W2_; T = T2_; break;
            case 3: W = W3; T = T3; break;
            case 4: W = W4; T = T4; break;
            default: W = W5; T = T5; break;
        }
        int i = (blk & 63) * 256 + threadIdx.x;   // 0..16383, i = k*128 + n
        int k = i >> 7, n = i & 127;
        int nt = n >> 4, mr = n & 15;
        int kc = k >> 5, rem = k & 31, quad = rem >> 3, j = rem & 7;
        T[(nt * 4 + kc) * 512 + quad * 128 + mr * 8 + j] = f2b(W[i]);
    } else if (blk < 12884) {
        int i = (blk - 384) * 256 + threadIdx.x;  // float4 chunks, 3,200,000 total
        if (i < 3200000) {
            float4 v = ((const float4*)x)[i];
            ushort4 o;
            o.x = f2b(v.x); o.y = f2b(v.y); o.z = f2b(v.z); o.w = f2b(v.w);
            ((ushort4*)xb)[i] = o;
        }
    } else {
        int i = (blk - 12884) * 256 + threadIdx.x;
        uint4 z = {0u, 0u, 0u, 0u};
        if (i < 256) dob4[i] = z;     // zero d_out scratch head (bcur)
        if (i < 16) xs0[i] = z;       // zero sentinel row xb[N_NODES]
    }
}

// ---------------- CSR build (bucket-local, LDS atomics only, degrees padded to %4) ----------------
// ebuf packed u32: (dst&1023)<<22 | src  (src < 2^17) -- halves bin write +
// bucket_all read traffic vs the R8 u64 form.

__global__ __launch_bounds__(256) void bin_kernel(const int* __restrict__ src,
                                                  const int* __restrict__ dst,
                                                  int* __restrict__ bcur,
                                                  unsigned int* __restrict__ ebuf) {
    __shared__ int h[NBUCK];
    __shared__ int base[NBUCK];
    int tid = threadIdx.x;
    if (tid < NBUCK) h[tid] = 0;
    __syncthreads();
    int e0 = blockIdx.x * 2048;
    int myd[8], mys[8];
#pragma unroll
    for (int i = 0; i < 8; i++) {
        int e = e0 + tid + i * 256;
        int dv = (e < N_EDGES) ? dst[e] : -1;
        myd[i] = dv;
        mys[i] = (e < N_EDGES) ? src[e] : 0;
        if (dv >= 0) atomicAdd(&h[dv >> 10], 1);
    }
    __syncthreads();
    if (tid < NBUCK) {
        int c = h[tid];
        base[tid] = (c > 0) ? (tid * CAP + atomicAdd(&bcur[tid], c)) : 0;
        h[tid] = 0;
    }
    __syncthreads();
#pragma unroll
    for (int i = 0; i < 8; i++) {
        int dv = myd[i];
        if (dv >= 0) {
            int b = dv >> 10;
            int p = base[b] + atomicAdd(&h[b], 1);
            if (p < (b + 1) * CAP)
                ebuf[p] = ((unsigned int)(dv & 1023) << 22) | (unsigned int)mys[i];
        }
    }
}

// One kernel per bucket: LDS hist -> %4-padded LDS scan -> off/offe -> LDS-atomic
// scatter into the bucket's fixed-stride csr slab -> sentinel pads.
__global__ __launch_bounds__(1024) void bucket_all_kernel(const unsigned int* __restrict__ ebuf,
                                                          const int* __restrict__ bcur,
                                                          int* __restrict__ off,
                                                          int* __restrict__ offe,
                                                          int* __restrict__ csr) {
    __shared__ int hist[1024];
    __shared__ int sc[1024];
    __shared__ int cnt[1024];
    int b = blockIdx.x, tid = threadIdx.x;
    int nE = bcur[b]; if (nE > CAP) nE = CAP;
    int base = b * PCAP;
    const unsigned int* slab = ebuf + (size_t)b * CAP;
    hist[tid] = 0;
    cnt[tid] = 0;
    __syncthreads();
    for (int i = tid; i < nE; i += 1024)
        atomicAdd(&hist[slab[i] >> 22], 1);
    __syncthreads();
    int node = b * 1024 + tid;
    int d = hist[tid];
    int dp = (node < N_NODES) ? ((d + 3) & ~3) : 0;
    sc[tid] = dp;
    __syncthreads();
#pragma unroll
    for (int s = 1; s < 1024; s <<= 1) {
        int t = (tid >= s) ? sc[tid - s] : 0;
        __syncthreads();
        sc[tid] += t;
        __syncthreads();
    }
    int excl = sc[tid] - dp;
    sc[tid] = excl;
    if (node < N_NODES) {
        off[node] = base + excl;
        offe[node] = base + excl + dp;
    }
    __syncthreads();
    for (int i = tid; i < nE; i += 1024) {
        unsigned int e = slab[i];
        int dd = e >> 22;
        int pos = sc[dd] + atomicAdd(&cnt[dd], 1);
        csr[base + pos] = (int)(e & 0x3FFFFFu);
    }
    for (int j = d; j < dp; j++) csr[base + excl + j] = N_NODES;  // <=3 pads/node
}

// ---------------- aggregation: t[i] = x[i] + sum_{j in N_in(i)} x[j] ----------------
// Gather side: R8-verified (1 node/wave, 16 dword-gathers in flight, %4-padded
// CSR, zero sentinel row). Store side NEW: P is written in MFMA-FRAGMENT ORDER
// so the mlp A-loads become contiguous 1KB wave-reads (same trick that cut 74us
// on the W operand in R8; the mlp A-load had the identical 16-segment/instr
// fragmentation). Layout (shorts): P[((B*8 + s*4 + kc)*64 + quad*16 + mr)*8 + j]
// holds row (B*32 + s*16 + mr) column (kc*32 + quad*8 + j). agg lane l of node's
// wave holds columns 2l,2l+1 -> one dword store at
// ((B*8+s*4+(l>>4))*64 + ((l>>2)&3)*16 + mr)*4 + (l&3).

__global__ __launch_bounds__(256) void agg_bf16(const unsigned int* __restrict__ xb,
                                                const int* __restrict__ off,
                                                const int* __restrict__ offe,
                                                const int* __restrict__ csr,
                                                unsigned int* __restrict__ Pf) {
    int node = blockIdx.x * 4 + (threadIdx.x >> 6);
    int lane = threadIdx.x & 63;
    unsigned int v = xb[(size_t)node * 64 + lane];
    float ax = b2f_lo(v), ay = b2f_hi(v);
    int k = off[node], e = offe[node];
    for (; k + 16 <= e; k += 16) {
        int idx[16];
        unsigned int g[16];
#pragma unroll
        for (int i = 0; i < 16; i++) idx[i] = csr[k + i];
#pragma unroll
        for (int i = 0; i < 16; i++) g[i] = xb[(size_t)idx[i] * 64 + lane];
#pragma unroll
        for (int i = 0; i < 16; i++) { ax += b2f_lo(g[i]); ay += b2f_hi(g[i]); }
    }
    if (k + 8 <= e) {
        int idx[8];
        unsigned int g[8];
#pragma unroll
        for (int i = 0; i < 8; i++) idx[i] = csr[k + i];
#pragma unroll
        for (int i = 0; i < 8; i++) g[i] = xb[(size_t)idx[i] * 64 + lane];
#pragma unroll
        for (int i = 0; i < 8; i++) { ax += b2f_lo(g[i]); ay += b2f_hi(g[i]); }
        k += 8;
    }
    if (k < e) {
        int idx[4];
        unsigned int g[4];
#pragma unroll
        for (int i = 0; i < 4; i++) idx[i] = csr[k + i];
#pragma unroll
        for (int i = 0; i < 4; i++) g[i] = xb[(size_t)idx[i] * 64 + lane];
#pragma unroll
        for (int i = 0; i < 4; i++) { ax += b2f_lo(g[i]); ay += b2f_hi(g[i]); }
    }
    unsigned int packed = (unsigned int)f2b(ax) | ((unsigned int)f2b(ay) << 16);
    int B = node >> 5, sblk = (node >> 4) & 1, mr = node & 15;
    size_t didx = ((size_t)(B * 8 + sblk * 4 + (lane >> 4)) * 64
                   + ((lane >> 2) & 3) * 16 + mr) * 4 + (lane & 3);
    Pf[didx] = packed;
}

// ---------------- fused MLP: y = relu(relu(t @ W1 + b1) @ W2 + b2) ----------------
// A in fragment order: a0/a1 loads are contiguous 1KB wave-reads (one 64B-aligned
// 16B chunk per lane). W in fragment order (R8-verified). 128-thr blocks.

template <bool OUT_F32>
__global__ __launch_bounds__(128) void mlp_mfma(const unsigned short* __restrict__ A,
                                                const unsigned short* __restrict__ W1f,
                                                const float* __restrict__ bias1,
                                                const unsigned short* __restrict__ W2f,
                                                const float* __restrict__ bias2,
                                                void* __restrict__ out) {
    __shared__ char smem[2 * 8704];
    int tid = threadIdx.x;
    int wave = tid >> 6, lane = tid & 63;
    int quad = lane >> 4, mr = lane & 15;
    int m_base = blockIdx.x * 64 + wave * 32;
    int B = blockIdx.x * 2 + wave;
    if (B > NBLK32 - 1) B = NBLK32 - 1;   // last wave of last block; stores masked by gm

    unsigned short* ust = (unsigned short*)(smem + wave * 8704);

    // ---- GEMM1: u = relu(t @ W1 + b1), both strips; A-loads fully coalesced ----
    bf16x8 a0[4], a1[4];
#pragma unroll
    for (int kc = 0; kc < 4; kc++) {
        a0[kc] = *(const bf16x8*)(A + ((size_t)(B * 8 + kc) * 64 + lane) * 8);
        a1[kc] = *(const bf16x8*)(A + ((size_t)(B * 8 + 4 + kc) * 64 + lane) * 8);
    }

    f32x4 acc0[8], acc1[8];
#pragma unroll
    for (int nt = 0; nt < 8; nt++) { acc0[nt] = (f32x4)0.0f; acc1[nt] = (f32x4)0.0f; }
#pragma unroll
    for (int nt = 0; nt < 8; nt++) {
#pragma unroll
        for (int kc = 0; kc < 4; kc++) {
            bf16x8 b = *(const bf16x8*)(W1f + (nt * 4 + kc) * 512 + lane * 8);
            acc0[nt] = __builtin_amdgcn_mfma_f32_16x16x32_bf16(a0[kc], b, acc0[nt], 0, 0, 0);
            acc1[nt] = __builtin_amdgcn_mfma_f32_16x16x32_bf16(a1[kc], b, acc1[nt], 0, 0, 0);
        }
    }
    // C layout: col(n) = mr, row(m in strip) = quad*4 + r
#pragma unroll
    for (int nt = 0; nt < 8; nt++) {
        float bv = bias1[nt * 16 + mr];
#pragma unroll
        for (int r = 0; r < 4; r++) {
            ust[(quad * 4 + r) * 136 + nt * 16 + mr] = f2b(fmaxf(acc0[nt][r] + bv, 0.0f));
            ust[2176 + (quad * 4 + r) * 136 + nt * 16 + mr] = f2b(fmaxf(acc1[nt][r] + bv, 0.0f));
        }
    }

    // ---- GEMM2: y = relu(u @ W2 + b2), both strips ----
#pragma unroll
    for (int kc = 0; kc < 4; kc++) {
        a0[kc] = *(const bf16x8*)&ust[mr * 136 + kc * 32 + quad * 8];
        a1[kc] = *(const bf16x8*)&ust[2176 + mr * 136 + kc * 32 + quad * 8];
    }
#pragma unroll
    for (int nt = 0; nt < 8; nt++) { acc0[nt] = (f32x4)0.0f; acc1[nt] = (f32x4)0.0f; }
#pragma unroll
    for (int nt = 0; nt < 8; nt++) {
#pragma unroll
        for (int kc = 0; kc < 4; kc++) {
            bf16x8 b = *(const bf16x8*)(W2f + (nt * 4 + kc) * 512 + lane * 8);
            acc0[nt] = __builtin_amdgcn_mfma_f32_16x16x32_bf16(a0[kc], b, acc0[nt], 0, 0, 0);
            acc1[nt] = __builtin_amdgcn_mfma_f32_16x16x32_bf16(a1[kc], b, acc1[nt], 0, 0, 0);
        }
    }

    // ---- epilogue: stage each strip in LDS, coalesced store (u-strips dead now) ----
    if (OUT_F32) {
        float* st = (float*)ust;   // 16 x 132 f32 = 8448 B, fits in the 8704 B wave region
        const int S = 132;
        float* op = (float*)out;
#pragma unroll
        for (int s = 0; s < 2; s++) {
#pragma unroll
            for (int nt = 0; nt < 8; nt++) {
                float bv = bias2[nt * 16 + mr];
#pragma unroll
                for (int r = 0; r < 4; r++) {
                    float v = s ? acc1[nt][r] : acc0[nt][r];
                    st[(quad * 4 + r) * S + nt * 16 + mr] = fmaxf(v + bv, 0.0f);
                }
            }
#pragma unroll
            for (int it = 0; it < 8; it++) {
                int linear = lane + it * 64;
                int row = linear >> 5, col = (linear & 31) << 2;
                int gm = m_base + s * 16 + row;
                if (gm < N_NODES) {
                    float4 val = *(float4*)&st[row * S + col];
                    *(float4*)(op + (size_t)gm * D + col) = val;
                }
            }
        }
    } else {
        const int S = 136;
        unsigned short* op = (unsigned short*)out;
#pragma unroll
        for (int s = 0; s < 2; s++) {
            unsigned short* st = ust + s * 2176;
#pragma unroll
            for (int nt = 0; nt < 8; nt++) {
                float bv = bias2[nt * 16 + mr];
#pragma unroll
                for (int r = 0; r < 4; r++) {
                    float v = s ? acc1[nt][r] : acc0[nt][r];
                    st[(quad * 4 + r) * S + nt * 16 + mr] = f2b(fmaxf(v + bv, 0.0f));
                }
            }
#pragma unroll
            for (int it = 0; it < 4; it++) {
                int linear = lane + it * 64;
                int row = linear >> 4, col = (linear & 15) << 3;
                int gm = m_base + s * 16 + row;
                if (gm < N_NODES) {
                    uint4 val = *(uint4*)&st[row * S + col];
                    *(uint4*)(op + (size_t)gm * D + col) = val;
                }
            }
        }
    }
}

// ---------------- launch ----------------

extern "C" void kernel_launch(void* const* d_in, const int* in_sizes, int n_in,
                              void* d_out, int out_size, void* d_ws, size_t ws_size,
                              hipStream_t stream) {
    const float* x = (const float*)d_in[0];
    const int* ei = (const int*)d_in[1];
    const int* srcv = ei;
    const int* dstv = ei + N_EDGES;
    const float* W1[3] = {(const float*)d_in[2], (const float*)d_in[6], (const float*)d_in[10]};
    const float* b1[3] = {(const float*)d_in[3], (const float*)d_in[7], (const float*)d_in[11]};
    const float* W2[3] = {(const float*)d_in[4], (const float*)d_in[8], (const float*)d_in[12]};
    const float* b2[3] = {(const float*)d_in[5], (const float*)d_in[9], (const float*)d_in[13]};

    // ws layout (high-water 52,248,832):
    char* ws = (char*)d_ws;
    int* off  = (int*)ws;                                    // N ints @ 0
    int* offe = (int*)(ws + 400000);                         // N ints
    unsigned short* Wt[6];                                   // 6 x 32KB @ 800,000 (fragment order)
    for (int i = 0; i < 6; i++) Wt[i] = (unsigned short*)(ws + 800000 + i * 32768);
    unsigned short* xb = (unsigned short*)(ws + 1048576);    // (N+1)*256 B row-major, sentinel row N
    unsigned short* P  = (unsigned short*)(ws + 26648832);   // N*256 B FRAGMENT ORDER, ends 52,248,832

    // d_out scratch (all reads complete before mlp<true> writes d_out):
    char* dob = (char*)d_out;
    int* bcur = (int*)(dob);                          // NBUCK ints (zeroed by prep)
    unsigned int* ebuf = (unsigned int*)(dob + 1048576);  // NBUCK*CAP u32 = 8.03MB, ends 9,076,736
    int* csr  = (int*)(dob + 10485760);               // NBUCK*PCAP ints = 9.63MB, ends 20,119,552

    // --- prep: zero bcur + sentinel row + weights->fragment order + convert x ---
    prep_kernel<<<12885, 256, 0, stream>>>(
        x, xb,
        W1[0], W2[0], W1[1], W2[1], W1[2], W2[2],
        Wt[0], Wt[1], Wt[2], Wt[3], Wt[4], Wt[5],
        (uint4*)dob, (uint4*)(xb + (size_t)N_NODES * D));

    // --- CSR build: 2 kernels (bin -> fused hist/scan/scatter per bucket) ---
    bin_kernel<<<782, 256, 0, stream>>>(srcv, dstv, bcur, ebuf);
    bucket_all_kernel<<<NBUCK, 1024, 0, stream>>>(ebuf, bcur, off, offe, csr);

    const int agg_grid = 25000;                        // 4 nodes/block, 1 node/wave
    const int mlp_grid = 1563;                         // 64 rows/block, 2 waves

    // layer 0: agg xb->P(frag), mlp P->xb
    agg_bf16<<<agg_grid, 256, 0, stream>>>((const unsigned int*)xb, off, offe, csr, (unsigned int*)P);
    mlp_mfma<false><<<mlp_grid, 128, 0, stream>>>(P, Wt[0], b1[0], Wt[1], b2[0], xb);
    // layer 1
    agg_bf16<<<agg_grid, 256, 0, stream>>>((const unsigned int*)xb, off, offe, csr, (unsigned int*)P);
    mlp_mfma<false><<<mlp_grid, 128, 0, stream>>>(P, Wt[2], b1[1], Wt[3], b2[1], xb);
    // layer 2
    agg_bf16<<<agg_grid, 256, 0, stream>>>((const unsigned int*)xb, off, offe, csr, (unsigned int*)P);
    mlp_mfma<true><<<mlp_grid, 128, 0, stream>>>(P, Wt[4], b1[2], Wt[5], b2[2], d_out);
}

// Round 12
// 412.654 us; speedup vs baseline: 1.8095x; 1.0019x over previous
//
#include <hip/hip_runtime.h>

#define N_NODES 100000
#define N_EDGES 1600000
#define D 128
#define NBUCK 98          // ceil(N_NODES / 1024), bucket = dst >> 10
#define CAP 20480         // ebuf slab capacity per bucket (raw edges); mean 16384, sigma~127
#define PCAP 24576        // csr slab capacity per bucket (%4-padded); max = CAP + 3*1024 = 23552
#define NBLK32 3125       // N_NODES / 32 row-blocks (exact)

typedef __attribute__((ext_vector_type(8))) short bf16x8;
typedef __attribute__((ext_vector_type(4))) float f32x4;
typedef unsigned long long u64;

__device__ __forceinline__ float b2f_lo(unsigned int u) {
    return __builtin_bit_cast(float, u << 16);
}
__device__ __forceinline__ float b2f_hi(unsigned int u) {
    return __builtin_bit_cast(float, u & 0xFFFF0000u);
}
__device__ __forceinline__ unsigned short f2b(float f) {
    unsigned int u = __builtin_bit_cast(unsigned int, f);
    u += 0x7FFFu + ((u >> 16) & 1u);
    return (unsigned short)(u >> 16);
}

// ---------------- prep: zero scratch + weights -> MFMA-fragment order + convert x ----------------

__global__ __launch_bounds__(256) void prep_kernel(
    const float* __restrict__ x, unsigned short* __restrict__ xb,
    const float* __restrict__ W0, const float* __restrict__ W1_, const float* __restrict__ W2_,
    const float* __restrict__ W3, const float* __restrict__ W4, const float* __restrict__ W5,
    unsigned short* __restrict__ T0, unsigned short* __restrict__ T1_,
    unsigned short* __restrict__ T2_, unsigned short* __restrict__ T3,
    unsigned short* __restrict__ T4, unsigned short* __restrict__ T5,
    uint4* __restrict__ dob4, uint4* __restrict__ xs0) {
    int blk = blockIdx.x;
    if (blk < 384) {
        const float* W;
        unsigned short* T;
        switch (blk >> 6) {
            case 0: W = W0; T = T0; break;
            case 1: W = W1_; T = T1_; break;
            case 2: W = W2_; T = T2_; break;
            case 3: W = W3; T = T3; break;
            case 4: W = W4; T = T4; break;
            default: W = W5; T = T5; break;
        }
        int i = (blk & 63) * 256 + threadIdx.x;   // 0..16383, i = k*128 + n
        int k = i >> 7, n = i & 127;
        int nt = n >> 4, mr = n & 15;
        int kc = k >> 5, rem = k & 31, quad = rem >> 3, j = rem & 7;
        T[(nt * 4 + kc) * 512 + quad * 128 + mr * 8 + j] = f2b(W[i]);
    } else if (blk < 12884) {
        int i = (blk - 384) * 256 + threadIdx.x;  // float4 chunks, 3,200,000 total
        if (i < 3200000) {
            float4 v = ((const float4*)x)[i];
            ushort4 o;
            o.x = f2b(v.x); o.y = f2b(v.y); o.z = f2b(v.z); o.w = f2b(v.w);
            ((ushort4*)xb)[i] = o;
        }
    } else {
        int i = (blk - 12884) * 256 + threadIdx.x;
        uint4 z = {0u, 0u, 0u, 0u};
        if (i < 256) dob4[i] = z;     // zero d_out scratch head (bcur)
        if (i < 16) xs0[i] = z;       // zero sentinel row xb[N_NODES]
    }
}

// ---------------- CSR build (bucket-local, LDS atomics only, degrees padded to %4) ----------------
// ebuf packed u32: (dst&1023)<<22 | src  (src < 2^17).

__global__ __launch_bounds__(256) void bin_kernel(const int* __restrict__ src,
                                                  const int* __restrict__ dst,
                                                  int* __restrict__ bcur,
                                                  unsigned int* __restrict__ ebuf) {
    __shared__ int h[NBUCK];
    __shared__ int base[NBUCK];
    int tid = threadIdx.x;
    if (tid < NBUCK) h[tid] = 0;
    __syncthreads();
    int e0 = blockIdx.x * 2048;
    int myd[8], mys[8];
#pragma unroll
    for (int i = 0; i < 8; i++) {
        int e = e0 + tid + i * 256;
        int dv = (e < N_EDGES) ? dst[e] : -1;
        myd[i] = dv;
        mys[i] = (e < N_EDGES) ? src[e] : 0;
        if (dv >= 0) atomicAdd(&h[dv >> 10], 1);
    }
    __syncthreads();
    if (tid < NBUCK) {
        int c = h[tid];
        base[tid] = (c > 0) ? (tid * CAP + atomicAdd(&bcur[tid], c)) : 0;
        h[tid] = 0;
    }
    __syncthreads();
#pragma unroll
    for (int i = 0; i < 8; i++) {
        int dv = myd[i];
        if (dv >= 0) {
            int b = dv >> 10;
            int p = base[b] + atomicAdd(&h[b], 1);
            if (p < (b + 1) * CAP)
                ebuf[p] = ((unsigned int)(dv & 1023) << 22) | (unsigned int)mys[i];
        }
    }
}

// One kernel per bucket: LDS hist -> %4-padded LDS scan -> off/offe -> LDS-atomic
// scatter into the bucket's fixed-stride csr slab -> sentinel pads.
__global__ __launch_bounds__(1024) void bucket_all_kernel(const unsigned int* __restrict__ ebuf,
                                                          const int* __restrict__ bcur,
                                                          int* __restrict__ off,
                                                          int* __restrict__ offe,
                                                          int* __restrict__ csr) {
    __shared__ int hist[1024];
    __shared__ int sc[1024];
    __shared__ int cnt[1024];
    int b = blockIdx.x, tid = threadIdx.x;
    int nE = bcur[b]; if (nE > CAP) nE = CAP;
    int base = b * PCAP;
    const unsigned int* slab = ebuf + (size_t)b * CAP;
    hist[tid] = 0;
    cnt[tid] = 0;
    __syncthreads();
    for (int i = tid; i < nE; i += 1024)
        atomicAdd(&hist[slab[i] >> 22], 1);
    __syncthreads();
    int node = b * 1024 + tid;
    int d = hist[tid];
    int dp = (node < N_NODES) ? ((d + 3) & ~3) : 0;
    sc[tid] = dp;
    __syncthreads();
#pragma unroll
    for (int s = 1; s < 1024; s <<= 1) {
        int t = (tid >= s) ? sc[tid - s] : 0;
        __syncthreads();
        sc[tid] += t;
        __syncthreads();
    }
    int excl = sc[tid] - dp;
    sc[tid] = excl;
    if (node < N_NODES) {
        off[node] = base + excl;
        offe[node] = base + excl + dp;
    }
    __syncthreads();
    for (int i = tid; i < nE; i += 1024) {
        unsigned int e = slab[i];
        int dd = e >> 22;
        int pos = sc[dd] + atomicAdd(&cnt[dd], 1);
        csr[base + pos] = (int)(e & 0x3FFFFFu);
    }
    for (int j = d; j < dp; j++) csr[base + excl + j] = N_NODES;  // <=3 pads/node
}

// ---------------- aggregation: t[i] = x[i] + sum_{j in N_in(i)} x[j] ----------------
// Gather: R8-verified (1 node/wave, 16 dword-gathers in flight, %4-padded CSR,
// zero sentinel row). Store: P in MFMA-fragment order (feeds mlp's coalesced
// A-loads; verified R11).

__global__ __launch_bounds__(256) void agg_bf16(const unsigned int* __restrict__ xb,
                                                const int* __restrict__ off,
                                                const int* __restrict__ offe,
                                                const int* __restrict__ csr,
                                                unsigned int* __restrict__ Pf) {
    int node = blockIdx.x * 4 + (threadIdx.x >> 6);
    int lane = threadIdx.x & 63;
    unsigned int v = xb[(size_t)node * 64 + lane];
    float ax = b2f_lo(v), ay = b2f_hi(v);
    int k = off[node], e = offe[node];
    for (; k + 16 <= e; k += 16) {
        int idx[16];
        unsigned int g[16];
#pragma unroll
        for (int i = 0; i < 16; i++) idx[i] = csr[k + i];
#pragma unroll
        for (int i = 0; i < 16; i++) g[i] = xb[(size_t)idx[i] * 64 + lane];
#pragma unroll
        for (int i = 0; i < 16; i++) { ax += b2f_lo(g[i]); ay += b2f_hi(g[i]); }
    }
    if (k + 8 <= e) {
        int idx[8];
        unsigned int g[8];
#pragma unroll
        for (int i = 0; i < 8; i++) idx[i] = csr[k + i];
#pragma unroll
        for (int i = 0; i < 8; i++) g[i] = xb[(size_t)idx[i] * 64 + lane];
#pragma unroll
        for (int i = 0; i < 8; i++) { ax += b2f_lo(g[i]); ay += b2f_hi(g[i]); }
        k += 8;
    }
    if (k < e) {
        int idx[4];
        unsigned int g[4];
#pragma unroll
        for (int i = 0; i < 4; i++) idx[i] = csr[k + i];
#pragma unroll
        for (int i = 0; i < 4; i++) g[i] = xb[(size_t)idx[i] * 64 + lane];
#pragma unroll
        for (int i = 0; i < 4; i++) { ax += b2f_lo(g[i]); ay += b2f_hi(g[i]); }
    }
    unsigned int packed = (unsigned int)f2b(ax) | ((unsigned int)f2b(ay) << 16);
    int B = node >> 5, sblk = (node >> 4) & 1, mr = node & 15;
    size_t didx = ((size_t)(B * 8 + sblk * 4 + (lane >> 4)) * 64
                   + ((lane >> 2) & 3) * 16 + mr) * 4 + (lane & 3);
    Pf[didx] = packed;
}

// ---------------- fused MLP: y = relu(relu(t @ W1 + b1) @ W2 + b2) ----------------
// 1 STRIP (16 rows) PER WAVE: 6250 waves (~28/CU, was 3126 at ~12/CU). The
// 2-strip amortization existed for the pre-R8 scattered b-loads; with W and A
// both in fragment order (contiguous 1KB wave-reads) the latency-hiding from
// 2.3x occupancy beats halved W reuse (W L2 traffic 200->400MB << 34.5TB/s).
// Per-wave LDS 4480B (f32 epilogue staged as 2x8-row passes) -> 8 blocks/CU.

template <bool OUT_F32>
__global__ __launch_bounds__(256) void mlp_mfma(const unsigned short* __restrict__ A,
                                                const unsigned short* __restrict__ W1f,
                                                const float* __restrict__ bias1,
                                                const unsigned short* __restrict__ W2f,
                                                const float* __restrict__ bias2,
                                                void* __restrict__ out) {
    __shared__ char smem[4 * 4480];
    int tid = threadIdx.x;
    int wave = tid >> 6, lane = tid & 63;
    int quad = lane >> 4, mr = lane & 15;
    int gw = blockIdx.x * 4 + wave;            // 0..6251 (6250 real)
    int gwc = (gw > 2 * NBLK32 - 1) ? (2 * NBLK32 - 1) : gw;
    int B = gwc >> 1, sh = gwc & 1;
    int m_base = gw * 16;                      // true base; >=N_NODES masks all stores

    unsigned short* ust = (unsigned short*)(smem + wave * 4480);

    // ---- GEMM1: u = relu(t @ W1 + b1); A-loads contiguous 1KB wave-reads ----
    bf16x8 a[4];
#pragma unroll
    for (int kc = 0; kc < 4; kc++)
        a[kc] = *(const bf16x8*)(A + ((size_t)(B * 8 + sh * 4 + kc) * 64 + lane) * 8);

    f32x4 acc[8];
#pragma unroll
    for (int nt = 0; nt < 8; nt++) acc[nt] = (f32x4)0.0f;
#pragma unroll
    for (int nt = 0; nt < 8; nt++) {
#pragma unroll
        for (int kc = 0; kc < 4; kc++) {
            bf16x8 b = *(const bf16x8*)(W1f + (nt * 4 + kc) * 512 + lane * 8);
            acc[nt] = __builtin_amdgcn_mfma_f32_16x16x32_bf16(a[kc], b, acc[nt], 0, 0, 0);
        }
    }
    // C layout: col(n) = mr, row = quad*4 + r
#pragma unroll
    for (int nt = 0; nt < 8; nt++) {
        float bv = bias1[nt * 16 + mr];
#pragma unroll
        for (int r = 0; r < 4; r++)
            ust[(quad * 4 + r) * 136 + nt * 16 + mr] = f2b(fmaxf(acc[nt][r] + bv, 0.0f));
    }

    // ---- GEMM2: y = relu(u @ W2 + b2) ----
#pragma unroll
    for (int kc = 0; kc < 4; kc++)
        a[kc] = *(const bf16x8*)&ust[mr * 136 + kc * 32 + quad * 8];
#pragma unroll
    for (int nt = 0; nt < 8; nt++) acc[nt] = (f32x4)0.0f;
#pragma unroll
    for (int nt = 0; nt < 8; nt++) {
#pragma unroll
        for (int kc = 0; kc < 4; kc++) {
            bf16x8 b = *(const bf16x8*)(W2f + (nt * 4 + kc) * 512 + lane * 8);
            acc[nt] = __builtin_amdgcn_mfma_f32_16x16x32_bf16(a[kc], b, acc[nt], 0, 0, 0);
        }
    }

    // ---- epilogue (u region dead after GEMM2 a-loads) ----
    if (OUT_F32) {
        float* st = (float*)ust;                // 8 x 132 f32 = 4224 B per pass
        const int S = 132;
        float* op = (float*)out;
#pragma unroll
        for (int p = 0; p < 2; p++) {
#pragma unroll
            for (int nt = 0; nt < 8; nt++) {
                float bv = bias2[nt * 16 + mr];
#pragma unroll
                for (int r = 0; r < 4; r++) {
                    int row16 = quad * 4 + r;
                    if ((row16 >> 3) == p)
                        st[(row16 & 7) * S + nt * 16 + mr] = fmaxf(acc[nt][r] + bv, 0.0f);
                }
            }
#pragma unroll
            for (int it = 0; it < 4; it++) {
                int linear = lane + it * 64;
                int row = linear >> 5, col = (linear & 31) << 2;
                int gm = m_base + p * 8 + row;
                if (gm < N_NODES) {
                    float4 val = *(float4*)&st[row * S + col];
                    *(float4*)(op + (size_t)gm * D + col) = val;
                }
            }
        }
    } else {
        const int S = 136;
        unsigned short* op = (unsigned short*)out;
#pragma unroll
        for (int nt = 0; nt < 8; nt++) {
            float bv = bias2[nt * 16 + mr];
#pragma unroll
            for (int r = 0; r < 4; r++)
                ust[(quad * 4 + r) * S + nt * 16 + mr] = f2b(fmaxf(acc[nt][r] + bv, 0.0f));
        }
#pragma unroll
        for (int it = 0; it < 4; it++) {
            int linear = lane + it * 64;
            int row = linear >> 4, col = (linear & 15) << 3;
            int gm = m_base + row;
            if (gm < N_NODES) {
                uint4 val = *(uint4*)&ust[row * S + col];
                *(uint4*)(op + (size_t)gm * D + col) = val;
            }
        }
    }
}

// ---------------- launch ----------------

extern "C" void kernel_launch(void* const* d_in, const int* in_sizes, int n_in,
                              void* d_out, int out_size, void* d_ws, size_t ws_size,
                              hipStream_t stream) {
    const float* x = (const float*)d_in[0];
    const int* ei = (const int*)d_in[1];
    const int* srcv = ei;
    const int* dstv = ei + N_EDGES;
    const float* W1[3] = {(const float*)d_in[2], (const float*)d_in[6], (const float*)d_in[10]};
    const float* b1[3] = {(const float*)d_in[3], (const float*)d_in[7], (const float*)d_in[11]};
    const float* W2[3] = {(const float*)d_in[4], (const float*)d_in[8], (const float*)d_in[12]};
    const float* b2[3] = {(const float*)d_in[5], (const float*)d_in[9], (const float*)d_in[13]};

    // ws layout (high-water 52,248,832):
    char* ws = (char*)d_ws;
    int* off  = (int*)ws;                                    // N ints @ 0
    int* offe = (int*)(ws + 400000);                         // N ints
    unsigned short* Wt[6];                                   // 6 x 32KB @ 800,000 (fragment order)
    for (int i = 0; i < 6; i++) Wt[i] = (unsigned short*)(ws + 800000 + i * 32768);
    unsigned short* xb = (unsigned short*)(ws + 1048576);    // (N+1)*256 B row-major, sentinel row N
    unsigned short* P  = (unsigned short*)(ws + 26648832);   // N*256 B FRAGMENT ORDER, ends 52,248,832

    // d_out scratch (all reads complete before mlp<true> writes d_out):
    char* dob = (char*)d_out;
    int* bcur = (int*)(dob);                          // NBUCK ints (zeroed by prep)
    unsigned int* ebuf = (unsigned int*)(dob + 1048576);  // NBUCK*CAP u32 = 8.03MB, ends 9,076,736
    int* csr  = (int*)(dob + 10485760);               // NBUCK*PCAP ints = 9.63MB, ends 20,119,552

    // --- prep: zero bcur + sentinel row + weights->fragment order + convert x ---
    prep_kernel<<<12885, 256, 0, stream>>>(
        x, xb,
        W1[0], W2[0], W1[1], W2[1], W1[2], W2[2],
        Wt[0], Wt[1], Wt[2], Wt[3], Wt[4], Wt[5],
        (uint4*)dob, (uint4*)(xb + (size_t)N_NODES * D));

    // --- CSR build: 2 kernels (bin -> fused hist/scan/scatter per bucket) ---
    bin_kernel<<<782, 256, 0, stream>>>(srcv, dstv, bcur, ebuf);
    bucket_all_kernel<<<NBUCK, 1024, 0, stream>>>(ebuf, bcur, off, offe, csr);

    const int agg_grid = 25000;                        // 4 nodes/block, 1 node/wave
    const int mlp_grid = 1563;                         // 4 waves/block, 16 rows/wave (6250 waves)

    // layer 0: agg xb->P(frag), mlp P->xb
    agg_bf16<<<agg_grid, 256, 0, stream>>>((const unsigned int*)xb, off, offe, csr, (unsigned int*)P);
    mlp_mfma<false><<<mlp_grid, 256, 0, stream>>>(P, Wt[0], b1[0], Wt[1], b2[0], xb);
    // layer 1
    agg_bf16<<<agg_grid, 256, 0, stream>>>((const unsigned int*)xb, off, offe, csr, (unsigned int*)P);
    mlp_mfma<false><<<mlp_grid, 256, 0, stream>>>(P, Wt[2], b1[1], Wt[3], b2[1], xb);
    // layer 2
    agg_bf16<<<agg_grid, 256, 0, stream>>>((const unsigned int*)xb, off, offe, csr, (unsigned int*)P);
    mlp_mfma<true><<<mlp_grid, 256, 0, stream>>>(P, Wt[4], b1[2], Wt[5], b2[2], d_out);
}